// Round 1
// baseline (1437.805 us; speedup 1.0000x reference)
//
#include <hip/hip_runtime.h>
#include <math.h>

#define N_ROWS 1000000
#define HDIM   256
#define BSEG   4096

__device__ __forceinline__ unsigned int enc_f32(float x) {
    unsigned int u = __float_as_uint(x);
    return (u & 0x80000000u) ? ~u : (u | 0x80000000u);
}

// Kernel 1: segment sum / count / max over sorted batch ids.
// One wave (64 lanes) per contiguous row range; lane l owns columns [4l, 4l+4).
extern "C" __global__ __launch_bounds__(256)
void seg_reduce_kernel(const float* __restrict__ A, const int* __restrict__ batch,
                       float* __restrict__ sums, unsigned int* __restrict__ maxk,
                       unsigned int* __restrict__ counts, int rows_per_wave)
{
    int wave = __builtin_amdgcn_readfirstlane((int)(blockIdx.x * 4 + (threadIdx.x >> 6)));
    int lane = threadIdx.x & 63;
    long long r0 = (long long)wave * rows_per_wave;
    if (r0 >= N_ROWS) return;
    long long r1 = r0 + rows_per_wave;
    if (r1 > N_ROWS) r1 = N_ROWS;

    const float4* __restrict__ A4 = reinterpret_cast<const float4*>(A);

    float sx = 0.f, sy = 0.f, sz = 0.f, sw = 0.f;
    float mx = -INFINITY, my = -INFINITY, mz = -INFINITY, mw = -INFINITY;
    int cnt = 0;
    int cur = -1;

    for (long long r = r0; r < r1; ++r) {
        int seg = batch[r];
        if (seg != cur) {
            if (cnt > 0) {
                size_t base = (size_t)cur * HDIM + 4 * lane;
                atomicAdd(&sums[base + 0], sx);
                atomicAdd(&sums[base + 1], sy);
                atomicAdd(&sums[base + 2], sz);
                atomicAdd(&sums[base + 3], sw);
                atomicMax(&maxk[base + 0], enc_f32(mx));
                atomicMax(&maxk[base + 1], enc_f32(my));
                atomicMax(&maxk[base + 2], enc_f32(mz));
                atomicMax(&maxk[base + 3], enc_f32(mw));
                if (lane == 0) atomicAdd(&counts[cur], (unsigned int)cnt);
            }
            cur = seg;
            sx = sy = sz = sw = 0.f;
            mx = my = mz = mw = -INFINITY;
            cnt = 0;
        }
        float4 a = A4[(size_t)r * 64 + lane];
        sx += a.x; sy += a.y; sz += a.z; sw += a.w;
        mx = fmaxf(mx, a.x); my = fmaxf(my, a.y);
        mz = fmaxf(mz, a.z); mw = fmaxf(mw, a.w);
        cnt++;
    }
    if (cnt > 0) {
        size_t base = (size_t)cur * HDIM + 4 * lane;
        atomicAdd(&sums[base + 0], sx);
        atomicAdd(&sums[base + 1], sy);
        atomicAdd(&sums[base + 2], sz);
        atomicAdd(&sums[base + 3], sw);
        atomicMax(&maxk[base + 0], enc_f32(mx));
        atomicMax(&maxk[base + 1], enc_f32(my));
        atomicMax(&maxk[base + 2], enc_f32(mz));
        atomicMax(&maxk[base + 3], enc_f32(mw));
        if (lane == 0) atomicAdd(&counts[cur], (unsigned int)cnt);
    }
}

// Kernel 2: fused  combined = [mean|sum|max] -> silu(combined@W1+b1)@W2+b2
// 16 graphs per block; thread j = output column; 16-row register tile.
// sums aliases d_out: each block reads only its own 16 rows (into LDS, before
// barrier) and writes the same 16 rows at the very end -> safe.
extern "C" __global__ __launch_bounds__(256)
void mlp_kernel(const float* __restrict__ sums, const unsigned int* __restrict__ maxk,
                const unsigned int* __restrict__ counts,
                const float* __restrict__ W1, const float* __restrict__ b1,
                const float* __restrict__ W2, const float* __restrict__ b2,
                float* __restrict__ out)
{
    __shared__ float smem[16 * 768];   // combined tile; first 16*256 reused as h
    const int tid = threadIdx.x;
    const int g0  = blockIdx.x * 16;

    // Stage combined[16][768] into LDS.
    #pragma unroll 4
    for (int r = 0; r < 16; ++r) {
        int g = g0 + r;
        unsigned int c = counts[g];
        float inv = 1.0f / fmaxf((float)c, 1.0f);
        float s = sums[(size_t)g * HDIM + tid];
        unsigned int mk = maxk[(size_t)g * HDIM + tid];
        unsigned int u = (mk & 0x80000000u) ? (mk ^ 0x80000000u) : ~mk;
        float mval = (c > 0u) ? __uint_as_float(u) : 0.0f;
        smem[r * 768 + tid]       = s * inv;   // mean
        smem[r * 768 + 256 + tid] = s;         // sum
        smem[r * 768 + 512 + tid] = mval;      // max (0 for empty segment)
    }
    __syncthreads();

    const int j = tid;

    // GEMM1: [16,768] @ W1[768,256] col j
    float acc[16];
    {
        float bb = b1[j];
        #pragma unroll
        for (int r = 0; r < 16; ++r) acc[r] = bb;
    }
    for (int k = 0; k < 768; k += 4) {
        float w0 = W1[(size_t)(k + 0) * HDIM + j];
        float w1 = W1[(size_t)(k + 1) * HDIM + j];
        float w2 = W1[(size_t)(k + 2) * HDIM + j];
        float w3 = W1[(size_t)(k + 3) * HDIM + j];
        #pragma unroll
        for (int r = 0; r < 16; ++r) {
            float4 a = *reinterpret_cast<const float4*>(&smem[r * 768 + k]);
            acc[r] = fmaf(a.x, w0, acc[r]);
            acc[r] = fmaf(a.y, w1, acc[r]);
            acc[r] = fmaf(a.z, w2, acc[r]);
            acc[r] = fmaf(a.w, w3, acc[r]);
        }
    }

    // silu, then reuse LDS (combined dead after this barrier) for h[16][256]
    __syncthreads();
    float* hbuf = smem;
    #pragma unroll
    for (int r = 0; r < 16; ++r) {
        float x = acc[r];
        hbuf[r * 256 + j] = x / (1.0f + __expf(-x));
    }
    __syncthreads();

    // GEMM2: [16,256] @ W2[256,256] col j
    float acc2[16];
    {
        float bb = b2[j];
        #pragma unroll
        for (int r = 0; r < 16; ++r) acc2[r] = bb;
    }
    for (int k = 0; k < 256; k += 4) {
        float w0 = W2[(size_t)(k + 0) * HDIM + j];
        float w1 = W2[(size_t)(k + 1) * HDIM + j];
        float w2 = W2[(size_t)(k + 2) * HDIM + j];
        float w3 = W2[(size_t)(k + 3) * HDIM + j];
        #pragma unroll
        for (int r = 0; r < 16; ++r) {
            float4 a = *reinterpret_cast<const float4*>(&hbuf[r * 256 + k]);
            acc2[r] = fmaf(a.x, w0, acc2[r]);
            acc2[r] = fmaf(a.y, w1, acc2[r]);
            acc2[r] = fmaf(a.z, w2, acc2[r]);
            acc2[r] = fmaf(a.w, w3, acc2[r]);
        }
    }
    #pragma unroll
    for (int r = 0; r < 16; ++r)
        out[(size_t)(g0 + r) * HDIM + j] = acc2[r];
}

extern "C" void kernel_launch(void* const* d_in, const int* in_sizes, int n_in,
                              void* d_out, int out_size, void* d_ws, size_t ws_size,
                              hipStream_t stream) {
    const float* A     = (const float*)d_in[0];
    const int*   batch = (const int*)d_in[1];
    const float* W1    = (const float*)d_in[2];
    const float* b1    = (const float*)d_in[3];
    const float* W2    = (const float*)d_in[4];
    const float* b2    = (const float*)d_in[5];
    float* out = (float*)d_out;

    // Workspace layout: [counts: BSEG u32][maxk: BSEG*HDIM u32]
    unsigned int* counts = (unsigned int*)d_ws;
    unsigned int* maxk   = counts + BSEG;
    float* sums = out;  // reuse d_out as the sum buffer (exactly [B,H] fp32)

    // Zero init: 0 is identity for sums, counts, and the max-key encoding.
    hipMemsetAsync(d_out, 0, (size_t)BSEG * HDIM * sizeof(float), stream);
    hipMemsetAsync(d_ws, 0, (size_t)BSEG * sizeof(unsigned int)
                          + (size_t)BSEG * HDIM * sizeof(unsigned int), stream);

    const int waves = 2048 * 4;                       // 32 waves/CU
    const int rpw   = (N_ROWS + waves - 1) / waves;   // 123
    seg_reduce_kernel<<<2048, 256, 0, stream>>>(A, batch, sums, maxk, counts, rpw);
    mlp_kernel<<<BSEG / 16, 256, 0, stream>>>(sums, maxk, counts, W1, b1, W2, b2, out);
}